// Round 3
// baseline (446.452 us; speedup 1.0000x reference)
//
#include <hip/hip_runtime.h>

#define N_NODES 50000
#define N_EDGES 800000
#define HEADS   8
#define HID     32
#define HC      256
#define NG      64
#define SCAN_BLOCKS ((N_NODES + 255) / 256)   // 196
#define GEMM_WAVES (N_NODES / 16)             // 3125 wave-tiles (16 nodes each)
#define GEMM_BLOCKS2 ((GEMM_WAVES * 2 + 3) / 4)  // 1563 (2 col-halves per tile)
#define HIST_BLOCKS2 ((N_EDGES + 2047) / 2048)   // 391 (8 edges/thread)

typedef unsigned short ushort_t;
typedef unsigned int   uint_t;
typedef __attribute__((ext_vector_type(8))) short short8;
typedef __attribute__((ext_vector_type(4))) float f32x4;

// ---- workspace layout (float offsets) ----
#define HB_OFF    0                // hb bf16, head-line layout: [n/2][head][2 nodes x 64B] = 25.6MB
#define Y_OFF     6400000          // y bf16 N*32 (800000 float slots) — L2-resident 3.2MB
#define Z_OFF     8000000          // z fp32 N*32
#define AS_OFF    9600000          // a_sT[h][n] fp32 (head-major, 8*50000)
#define AD_OFF    10000000         // a_dT[h][n] fp32 (head-major)
#define ROW_OFF   10400000         // int row[N+1] (block-local exclusive scan)
#define DEG_OFF   10450016         // int deg[N] [zero-init by k_init]
#define CSR_OFF   10500016         // int csr_src[N_EDGES]
#define GS_OFF    11300016         // int gstart[NG+1]
#define BSUM_OFF  11300088         // int bsum[SCAN_BLOCKS]
#define WGBT_OFF  11300288         // bf16 WgT[256][128] (16384 float slots), 16B aligned
#define W1BT_OFF  11316672         // bf16 W1T[32][256] (4096 float slots), 16B aligned
#define EPOS_OFF  11320768         // int epos[N_EDGES]
#define OUTB_OFF  12120768         // out bf16 N*256 (3.2M float slots), node-major 512B rows
#define WS_END    15320768

__device__ __forceinline__ ushort_t f2bf(float f) {
    uint_t u = __float_as_uint(f);
    u = (u + 0x7FFFu + ((u >> 16) & 1u)) >> 16;   // RNE
    return (ushort_t)u;
}
__device__ __forceinline__ float bf2f(ushort_t u) { return __uint_as_float((uint_t)u << 16); }
__device__ __forceinline__ float bf_lo(uint_t u) { return __uint_as_float(u << 16); }
__device__ __forceinline__ float bf_hi(uint_t u) { return __uint_as_float(u & 0xFFFF0000u); }

// hb address for (node, ch): line-disjoint per head so one XCD's head-slice
// is exactly 3.2MB of whole 128B lines (fits 4MB per-XCD L2).
__device__ __forceinline__ size_t hb_ofs(int node, int ch) {
    return ((size_t)(node >> 1) << 10) + (size_t)(ch >> 5) * 128 +
           ((size_t)(node & 1) << 6) + (size_t)(ch & 31) * 2;
}

// merged init: transposed bf16 W_gat (32768) + zero deg (12500 f4) + bf16 W1^T (8192)
__global__ __launch_bounds__(256) void k_init(const float* __restrict__ Wg,
                                              const float* __restrict__ W1,
                                              ushort_t* __restrict__ wgbT,
                                              ushort_t* __restrict__ w1bT,
                                              float* __restrict__ degf) {
    int id = blockIdx.x * 256 + threadIdx.x;
    if (id < 32768) {
        wgbT[(id & 255) * 128 + (id >> 8)] = f2bf(Wg[id]);
    } else if (id < 32768 + 12500) {
        ((float4*)degf)[id - 32768] = make_float4(0.f, 0.f, 0.f, 0.f);
    } else if (id < 32768 + 12500 + 8192) {
        int j = id - 32768 - 12500;                  // j = k*32 + n
        w1bT[(j & 31) * 256 + (j >> 5)] = f2bf(W1[j]);
    }
}

// ---------- fused: MFMA GEMM (hb, a_sT, a_dT)  ||  batched edge histogram ----------
// Swapped operands: D = W_frag * x_frag puts NODE in lane, CHANNEL in regs:
//  - hb stores: 8 packed 8B stores/lane (vs 64 scattered 2B) -> kills write-amp
//  - a_s/a_d: lane-local dots + 2 shuffles (vs 8x4x16 shuffle cascade)
// Col-split (wave = 16 nodes x 128 ch) doubles GEMM blocks: 782 -> 1563.
__global__ __launch_bounds__(256) void k_gemm_hist(const float* __restrict__ x,
                                                   const ushort_t* __restrict__ wgbT,
                                                   const float* __restrict__ att_s,
                                                   const float* __restrict__ att_d,
                                                   ushort_t* __restrict__ hb,
                                                   float* __restrict__ a_sT,
                                                   float* __restrict__ a_dT,
                                                   const int* __restrict__ ei,
                                                   int* __restrict__ deg,
                                                   int* __restrict__ epos) {
    if (blockIdx.x >= GEMM_BLOCKS2) {
        // histogram: 8 independent atomics per thread (latency pipelined)
        int base = (blockIdx.x - GEMM_BLOCKS2) * 2048 + threadIdx.x;
#pragma unroll
        for (int i = 0; i < 8; ++i) {
            int e = base + i * 256;
            if (e < N_EDGES) epos[e] = atomicAdd(&deg[ei[N_EDGES + e]], 1);
        }
        return;
    }
    int wid = blockIdx.x * 4 + (threadIdx.x >> 6);
    int tile = wid >> 1;
    if (tile >= GEMM_WAVES) return;
    int colbase = (wid & 1) * 128;
    int lane = threadIdx.x & 63;
    int n0 = tile * 16;
    int col = lane & 15, quad = lane >> 4;

    f32x4 acc[8];
#pragma unroll
    for (int i = 0; i < 8; ++i) acc[i] = (f32x4){0.f, 0.f, 0.f, 0.f};

    const float* xr = x + (size_t)(n0 + col) * 128 + quad * 8;
    const ushort_t* wbase = wgbT + (size_t)(colbase + col) * 128 + quad * 8;
#pragma unroll
    for (int kk = 0; kk < 4; ++kk) {
        float4 xa = *(const float4*)(xr + kk * 32);
        float4 xb = *(const float4*)(xr + kk * 32 + 4);
        short8 af;   // B-operand: B[k][node]
        af[0] = (short)f2bf(xa.x); af[1] = (short)f2bf(xa.y);
        af[2] = (short)f2bf(xa.z); af[3] = (short)f2bf(xa.w);
        af[4] = (short)f2bf(xb.x); af[5] = (short)f2bf(xb.y);
        af[6] = (short)f2bf(xb.z); af[7] = (short)f2bf(xb.w);
#pragma unroll
        for (int nt = 0; nt < 8; ++nt) {
            short8 wf = *(const short8*)(wbase + nt * 16 * 128 + kk * 32); // A[ch][k]
            acc[nt] = __builtin_amdgcn_mfma_f32_16x16x32_bf16(wf, af, acc[nt], 0, 0, 0);
        }
    }

    // ---- hb store: lane owns node n0+col; regs hold ch = colbase+nt*16+quad*4+r ----
    int node = n0 + col;
#pragma unroll
    for (int nt = 0; nt < 8; ++nt) {
        int ch0 = colbase + nt * 16 + quad * 4;
        uint2 o;
        o.x = (uint_t)f2bf(acc[nt][0]) | ((uint_t)f2bf(acc[nt][1]) << 16);
        o.y = (uint_t)f2bf(acc[nt][2]) | ((uint_t)f2bf(acc[nt][3]) << 16);
        *(uint2*)((char*)hb + hb_ofs(node, ch0)) = o;
    }

    // ---- a_sT/a_dT: 4 local heads; lane-local partial dot, reduce over quads ----
#pragma unroll
    for (int hl = 0; hl < 4; ++hl) {
        int hg = (colbase >> 5) + hl;
        float4 s0 = *(const float4*)(att_s + colbase + hl * 32 + quad * 4);
        float4 s1 = *(const float4*)(att_s + colbase + hl * 32 + 16 + quad * 4);
        float4 d0 = *(const float4*)(att_d + colbase + hl * 32 + quad * 4);
        float4 d1 = *(const float4*)(att_d + colbase + hl * 32 + 16 + quad * 4);
        f32x4 e = acc[2 * hl], f = acc[2 * hl + 1];
        float ps = e[0]*s0.x + e[1]*s0.y + e[2]*s0.z + e[3]*s0.w
                 + f[0]*s1.x + f[1]*s1.y + f[2]*s1.z + f[3]*s1.w;
        float pd = e[0]*d0.x + e[1]*d0.y + e[2]*d0.z + e[3]*d0.w
                 + f[0]*d1.x + f[1]*d1.y + f[2]*d1.z + f[3]*d1.w;
        ps += __shfl_xor(ps, 16, 64); ps += __shfl_xor(ps, 32, 64);
        pd += __shfl_xor(pd, 16, 64); pd += __shfl_xor(pd, 32, 64);
        if (quad == 0) {
            a_sT[(size_t)hg * N_NODES + node] = ps;   // 16 lanes -> 64B coalesced
            a_dT[(size_t)hg * N_NODES + node] = pd;
        }
    }
}

__global__ __launch_bounds__(256) void k_scan1(const int* __restrict__ deg,
                                               int* __restrict__ row,
                                               int* __restrict__ bsum) {
    __shared__ int s[256];
    int t = threadIdx.x;
    int i = blockIdx.x * 256 + t;
    int v = (i < N_NODES) ? deg[i] : 0;
    s[t] = v;
    __syncthreads();
    for (int off = 1; off < 256; off <<= 1) {
        int u = (t >= off) ? s[t - off] : 0;
        __syncthreads();
        s[t] += u;
        __syncthreads();
    }
    if (i < N_NODES) row[i] = s[t] - v;       // exclusive, block-local
    if (t == 255) bsum[blockIdx.x] = s[255];
}

__global__ __launch_bounds__(256) void k_scan2(int* __restrict__ bsum,
                                               const int* __restrict__ batch,
                                               int* __restrict__ gs) {
    __shared__ int s[256];
    int t = threadIdx.x;
    int v = (t < SCAN_BLOCKS) ? bsum[t] : 0;
    s[t] = v;
    __syncthreads();
    for (int off = 1; off < 256; off <<= 1) {
        int u = (t >= off) ? s[t - off] : 0;
        __syncthreads();
        s[t] += u;
        __syncthreads();
    }
    if (t < SCAN_BLOCKS) bsum[t] = s[t] - v;  // exclusive
    if (t <= NG) {
        int lo = 0, hi = N_NODES;
        while (lo < hi) {
            int mid = (lo + hi) >> 1;
            if (batch[mid] < t) lo = mid + 1; else hi = mid;
        }
        gs[t] = lo;
    }
}

// scatter: pure permutation write, zero atomics. row is block-local; add bsum inline
__global__ __launch_bounds__(256) void k_scatter(const int* __restrict__ ei,
                                                 const int* __restrict__ row,
                                                 const int* __restrict__ bsum,
                                                 const int* __restrict__ epos,
                                                 int* __restrict__ csr) {
    int e = blockIdx.x * 256 + threadIdx.x;
    if (e >= N_EDGES) return;
    int d = ei[N_EDGES + e];
    csr[row[d] + bsum[d >> 8] + epos[e]] = ei[e];
}

// ---------- fused GAT: head-sliced, XCD-pinned gather ----------
// blockIdx % 8 = head = XCD (round-robin dispatch): each XCD only ever touches
// its head's hb lines (3.2MB, L2-resident) -> FETCH should drop 221MB -> ~60MB.
// Wave = 1 node; 16 lanes x 4B cover the head's 64B slice; 4 edges per pass.
// Self-loop = virtual edge at index deg.
__global__ __launch_bounds__(256) void k_gat(const int* __restrict__ row,
                                             const int* __restrict__ bsum,
                                             const int* __restrict__ csr,
                                             const float* __restrict__ a_sT,
                                             const float* __restrict__ a_dT,
                                             const ushort_t* __restrict__ hb,
                                             const float* __restrict__ bg,
                                             ushort_t* __restrict__ outb) {
    int w = threadIdx.x >> 6, lane = threadIdx.x & 63;
    int h  = blockIdx.x & 7;
    int ng = blockIdx.x >> 3;
    int n  = ng * 4 + w;                   // N_NODES % 4 == 0
    int r0 = row[n] + bsum[n >> 8];
    int r1 = (n + 1 < N_NODES) ? row[n + 1] + bsum[(n + 1) >> 8] : N_EDGES;
    int deg = r1 - r0;
    int E = deg + 1;

    int es = lane >> 4, c2 = lane & 15;
    const float* asp = a_sT + (size_t)h * N_NODES;
    float ad2 = a_dT[(size_t)h * N_NODES + n];
    const char* hbase = (const char*)hb + h * 128 + c2 * 4;
    const int* cp = csr + r0;

    float a0 = 0.f, a1 = 0.f, psum = 0.f;
    int j = 0;

#define GAT_PASS(JJ, MASKED)                                                   \
    {                                                                          \
        int idx = (JJ) + es;                                                   \
        int src = (idx < deg) ? cp[idx] : n;                                   \
        float av = asp[src];                                                   \
        uint_t u = *(const uint_t*)(hbase + ((size_t)(src >> 1) << 10) +       \
                                    ((size_t)(src & 1) << 6));                 \
        float v = av + ad2;                                                    \
        v = fmaxf(v, 0.2f * v);                                                \
        float ev = __expf(v);                                                  \
        if (MASKED) ev = (idx < E) ? ev : 0.f;                                 \
        psum += ev;                                                            \
        a0 = fmaf(ev, bf_lo(u), a0);                                           \
        a1 = fmaf(ev, bf_hi(u), a1);                                           \
    }

    for (; j + 8 <= E; j += 8) {
        GAT_PASS(j, false)
        GAT_PASS(j + 4, false)
    }
    if (j + 4 <= E) { GAT_PASS(j, false) j += 4; }
    if (j < E)      { GAT_PASS(j, true) }
#undef GAT_PASS

    // reduce the 4 edge-slots
    psum += __shfl_xor(psum, 16, 64); psum += __shfl_xor(psum, 32, 64);
    a0   += __shfl_xor(a0,   16, 64); a0   += __shfl_xor(a0,   32, 64);
    a1   += __shfl_xor(a1,   16, 64); a1   += __shfl_xor(a1,   32, 64);

    if (es == 0) {
        float inv = 1.0f / psum;
        float2 bb = *(const float2*)(bg + h * 32 + c2 * 2);
        float o0 = fmaxf(fmaf(a0, inv, bb.x), 0.f);
        float o1 = fmaxf(fmaf(a1, inv, bb.y), 0.f);
        uint_t o = (uint_t)f2bf(o0) | ((uint_t)f2bf(o1) << 16);
        *(uint_t*)((char*)outb + ((size_t)n << 9) + h * 64 + c2 * 4) = o;
    }
}

// ---------- MFMA projection: y = out_bf @ W1  (50000x256x32), bf16 output ----------
__global__ __launch_bounds__(256) void k_gemm_y(const ushort_t* __restrict__ outb,
                                                const ushort_t* __restrict__ w1bT,
                                                ushort_t* __restrict__ yb) {
    int wave = blockIdx.x * 4 + (threadIdx.x >> 6);
    if (wave >= GEMM_WAVES) return;
    int lane = threadIdx.x & 63;
    int n0 = wave * 16;
    int col = lane & 15, quad = lane >> 4;

    f32x4 acc0 = (f32x4){0.f, 0.f, 0.f, 0.f};
    f32x4 acc1 = (f32x4){0.f, 0.f, 0.f, 0.f};
    const ushort_t* ar = outb + (size_t)(n0 + col) * 256 + quad * 8;
    const ushort_t* b0 = w1bT + col * 256 + quad * 8;
    const ushort_t* b1 = w1bT + (16 + col) * 256 + quad * 8;
#pragma unroll
    for (int kk = 0; kk < 8; ++kk) {
        short8 af  = *(const short8*)(ar + kk * 32);
        short8 bf0 = *(const short8*)(b0 + kk * 32);
        short8 bf1 = *(const short8*)(b1 + kk * 32);
        acc0 = __builtin_amdgcn_mfma_f32_16x16x32_bf16(af, bf0, acc0, 0, 0, 0);
        acc1 = __builtin_amdgcn_mfma_f32_16x16x32_bf16(af, bf1, acc1, 0, 0, 0);
    }
    ushort_t* yr = yb + (size_t)(n0 + quad * 4) * 32 + col;
#pragma unroll
    for (int r = 0; r < 4; ++r) {
        yr[r * 32]      = f2bf(acc0[r]);
        yr[r * 32 + 16] = f2bf(acc1[r]);
    }
}

// ---------- GIN on bf16 y (64 B rows, L2-resident) + MLP layer 2 ----------
__global__ __launch_bounds__(256) void k_gin_mlp(const int* __restrict__ row,
                                                 const int* __restrict__ bsum,
                                                 const int* __restrict__ csr,
                                                 const ushort_t* __restrict__ yb,
                                                 const float* __restrict__ b1,
                                                 const float* __restrict__ W2,
                                                 const float* __restrict__ b2,
                                                 float* __restrict__ z) {
    __shared__ float s_z[4][32];
    int g = threadIdx.x >> 6;
    int lane = threadIdx.x & 63;
    int n = blockIdx.x * 4 + g;
    int col = lane & 31, half = lane >> 5;
    int r0 = row[n] + bsum[n >> 8];
    int r1 = (n + 1 < N_NODES) ? row[n + 1] + bsum[(n + 1) >> 8] : N_EDGES;
    const char* ycol = (const char*)(yb + col);     // +sj*64B
    float acc = (half == 0) ? (bf2f(yb[(size_t)n * 32 + col]) + b1[col]) : 0.f;
    int j = r0 + half;                              // this half-wave's edges: stride 2
    for (; j + 6 < r1; j += 8) {
        int s0 = csr[j], s1 = csr[j + 2], s2 = csr[j + 4], s3 = csr[j + 6];
        float v0 = bf2f(*(const ushort_t*)(ycol + ((size_t)s0 << 6)));
        float v1 = bf2f(*(const ushort_t*)(ycol + ((size_t)s1 << 6)));
        float v2 = bf2f(*(const ushort_t*)(ycol + ((size_t)s2 << 6)));
        float v3 = bf2f(*(const ushort_t*)(ycol + ((size_t)s3 << 6)));
        acc += (v0 + v1) + (v2 + v3);
    }
    for (; j < r1; j += 2)
        acc += bf2f(*(const ushort_t*)(ycol + ((size_t)csr[j] << 6)));
    acc += __shfl_xor(acc, 32, 64);
    float z1 = fmaxf(acc, 0.f);
    if (lane < 32) s_z[g][col] = z1;               // wave-private; no barrier
    const float* zr = &s_z[g][0];
    int k0 = half * 16;
    float p = 0.f;
#pragma unroll
    for (int k = 0; k < 16; k += 4) {
        float4 zv = *(const float4*)(zr + k0 + k);
        p = fmaf(zv.x, W2[(k0 + k + 0) * 32 + col], p);
        p = fmaf(zv.y, W2[(k0 + k + 1) * 32 + col], p);
        p = fmaf(zv.z, W2[(k0 + k + 2) * 32 + col], p);
        p = fmaf(zv.w, W2[(k0 + k + 3) * 32 + col], p);
    }
    p += __shfl_xor(p, 32, 64);
    if (lane < 32) z[n * 32 + col] = fmaxf(p + b2[col], 0.f);
}

// one block per graph: mean-pool its contiguous z rows, then @Wf + bf
__global__ __launch_bounds__(128) void k_pool_final(const float* __restrict__ z,
                                                    const int* __restrict__ gs,
                                                    const float* __restrict__ Wf,
                                                    const float* __restrict__ bf,
                                                    float* __restrict__ outp) {
    __shared__ float part[4][32];
    __shared__ float sums[32];
    int g = blockIdx.x;
    int t = threadIdx.x;
    int col = t & 31, q = t >> 5;
    int r0 = gs[g], r1 = gs[g + 1];
    float s = 0.f;
    for (int r = r0 + q; r < r1; r += 4) s += z[r * 32 + col];
    part[q][col] = s;
    __syncthreads();
    if (t < 32) sums[t] = part[0][t] + part[1][t] + part[2][t] + part[3][t];
    __syncthreads();
    float inv = 1.0f / fmaxf((float)(r1 - r0), 1.0f);
    float acc = 0.f;
#pragma unroll
    for (int k = 0; k < 32; ++k)
        acc = fmaf(sums[k], Wf[k * 128 + t], acc);
    outp[g * 128 + t] = acc * inv + bf[t];
}

extern "C" void kernel_launch(void* const* d_in, const int* in_sizes, int n_in,
                              void* d_out, int out_size, void* d_ws, size_t ws_size,
                              hipStream_t stream) {
    const float* x     = (const float*)d_in[0];
    const int*   ei    = (const int*)d_in[1];
    const int*   batch = (const int*)d_in[2];
    const float* Wg    = (const float*)d_in[3];
    const float* att_s = (const float*)d_in[4];
    const float* att_d = (const float*)d_in[5];
    const float* bg    = (const float*)d_in[6];
    const float* W1    = (const float*)d_in[7];
    const float* b1    = (const float*)d_in[8];
    const float* W2    = (const float*)d_in[9];
    const float* b2    = (const float*)d_in[10];
    const float* Wf    = (const float*)d_in[11];
    const float* bf    = (const float*)d_in[12];
    float* ws = (float*)d_ws;

    ushort_t* hb   = (ushort_t*)(ws + HB_OFF);
    ushort_t* yb   = (ushort_t*)(ws + Y_OFF);
    float* z       = ws + Z_OFF;
    float* a_sT    = ws + AS_OFF;
    float* a_dT    = ws + AD_OFF;
    int*   row     = (int*)(ws + ROW_OFF);
    int*   deg     = (int*)(ws + DEG_OFF);
    int*   csr     = (int*)(ws + CSR_OFF);
    int*   gs      = (int*)(ws + GS_OFF);
    int*   bsum    = (int*)(ws + BSUM_OFF);
    ushort_t* wgbT = (ushort_t*)(ws + WGBT_OFF);
    ushort_t* w1bT = (ushort_t*)(ws + W1BT_OFF);
    int*   epos    = (int*)(ws + EPOS_OFF);
    ushort_t* outb = (ushort_t*)(ws + OUTB_OFF);

    // init: wgbT + zero deg + w1bT (one launch)
    k_init<<<(32768 + 12500 + 8192 + 255) / 256, 256, 0, stream>>>(Wg, W1, wgbT, w1bT, (float*)deg);

    // fused: MFMA projection (hb, a_sT, a_dT) || batched edge histogram
    k_gemm_hist<<<GEMM_BLOCKS2 + HIST_BLOCKS2, 256, 0, stream>>>(
        x, wgbT, att_s, att_d, hb, a_sT, a_dT, ei, deg, epos);

    // CSR: scans + atomic-free scatter
    k_scan1<<<SCAN_BLOCKS, 256, 0, stream>>>(deg, row, bsum);
    k_scan2<<<1, 256, 0, stream>>>(bsum, batch, gs);
    k_scatter<<<(N_EDGES + 255) / 256, 256, 0, stream>>>(ei, row, bsum, epos, csr);

    // fused GAT: head-sliced gather, blockIdx%8 = head = XCD
    k_gat<<<(N_NODES / 4) * 8, 256, 0, stream>>>(row, bsum, csr, a_sT, a_dT, hb, bg, outb);
    // MFMA projection y = out_bf @ W1 (bf16 out, L2-resident for GIN)
    k_gemm_y<<<(GEMM_WAVES + 3) / 4, 256, 0, stream>>>(outb, w1bT, yb);

    // GIN on bf16 y + MLP layer 2 -> z (one wave per node, no barriers)
    k_gin_mlp<<<N_NODES / 4, 256, 0, stream>>>(row, bsum, csr, yb, b1, W2, b2, z);

    // per-graph mean pool + final linear
    k_pool_final<<<NG, 128, 0, stream>>>(z, gs, Wf, bf, (float*)d_out);
}

// Round 4
// 346.279 us; speedup vs baseline: 1.2893x; 1.2893x over previous
//
#include <hip/hip_runtime.h>

#define N_NODES 50000
#define N_EDGES 800000
#define HEADS   8
#define HID     32
#define HC      256
#define NG      64
#define SCAN_BLOCKS ((N_NODES + 255) / 256)   // 196
#define GEMM_WAVES (N_NODES / 16)             // 3125 wave-tiles (16 nodes each)
#define GEMM_BLOCKS2 ((GEMM_WAVES * 2 + 3) / 4)  // 1563 (2 col-halves per tile)
#define HIST_BLOCKS2 ((N_EDGES + 2047) / 2048)   // 391 (8 edges/thread)

typedef unsigned short ushort_t;
typedef unsigned int   uint_t;
typedef __attribute__((ext_vector_type(8))) short short8;
typedef __attribute__((ext_vector_type(4))) float f32x4;

// ---- workspace layout (float offsets) ----
#define HB_OFF    0                // hb bf16 N*256 node-major 512B rows (25.6MB)
#define Y_OFF     6400000          // y bf16 N*32 — L2-resident 3.2MB
#define Z_OFF     8000000          // z fp32 N*32
#define AS_OFF    9600000          // a_s[n][h] fp32 node-major
#define AD_OFF    10000000         // a_d[n][h] fp32 node-major
#define ROW_OFF   10400000         // int row[N+1] (block-local exclusive scan)
#define DEG_OFF   10450016         // int deg[N] [zero-init by k_init]
#define CSR_OFF   10500016         // int csr_src[N_EDGES]
#define GS_OFF    11300016         // int gstart[NG+1]
#define BSUM_OFF  11300088         // int bsum[SCAN_BLOCKS]
#define WGBT_OFF  11300288         // bf16 WgT[256][128] (16384 float slots), 16B aligned
#define W1BT_OFF  11316672         // bf16 W1T[32][256] (4096 float slots), 16B aligned
#define EPOS_OFF  11320768         // int epos[N_EDGES]
#define OUTB_OFF  12120768         // out bf16 N*256 (3.2M float slots), node-major 512B rows
#define WS_END    15320768

__device__ __forceinline__ ushort_t f2bf(float f) {
    uint_t u = __float_as_uint(f);
    u = (u + 0x7FFFu + ((u >> 16) & 1u)) >> 16;   // RNE
    return (ushort_t)u;
}
__device__ __forceinline__ float bf2f(ushort_t u) { return __uint_as_float((uint_t)u << 16); }
__device__ __forceinline__ float bf_lo(uint_t u) { return __uint_as_float(u << 16); }
__device__ __forceinline__ float bf_hi(uint_t u) { return __uint_as_float(u & 0xFFFF0000u); }

// merged init: transposed bf16 W_gat (32768) + zero deg (12500 f4) + bf16 W1^T (8192)
__global__ __launch_bounds__(256) void k_init(const float* __restrict__ Wg,
                                              const float* __restrict__ W1,
                                              ushort_t* __restrict__ wgbT,
                                              ushort_t* __restrict__ w1bT,
                                              float* __restrict__ degf) {
    int id = blockIdx.x * 256 + threadIdx.x;
    if (id < 32768) {
        wgbT[(id & 255) * 128 + (id >> 8)] = f2bf(Wg[id]);
    } else if (id < 32768 + 12500) {
        ((float4*)degf)[id - 32768] = make_float4(0.f, 0.f, 0.f, 0.f);
    } else if (id < 32768 + 12500 + 8192) {
        int j = id - 32768 - 12500;                  // j = k*32 + n
        w1bT[(j & 31) * 256 + (j >> 5)] = f2bf(W1[j]);
    }
}

// ---------- fused: MFMA GEMM (hb, a_s, a_d)  ||  batched edge histogram ----------
// Swapped operands: D = W_frag * x_frag puts NODE in lane, CHANNEL in regs:
//  - hb stores: 8 packed 8B stores/lane into plain node-major rows
//  - a_s/a_d: lane-local dots + 2 shuffles (vs 8x4x16 shuffle cascade)
// Col-split (wave = 16 nodes x 128 ch) doubles GEMM parallelism: 782 -> 1563 blocks.
__global__ __launch_bounds__(256) void k_gemm_hist(const float* __restrict__ x,
                                                   const ushort_t* __restrict__ wgbT,
                                                   const float* __restrict__ att_s,
                                                   const float* __restrict__ att_d,
                                                   ushort_t* __restrict__ hb,
                                                   float* __restrict__ a_s,
                                                   float* __restrict__ a_d,
                                                   const int* __restrict__ ei,
                                                   int* __restrict__ deg,
                                                   int* __restrict__ epos) {
    if (blockIdx.x >= GEMM_BLOCKS2) {
        // histogram: 8 independent atomics per thread (latency pipelined)
        int base = (blockIdx.x - GEMM_BLOCKS2) * 2048 + threadIdx.x;
#pragma unroll
        for (int i = 0; i < 8; ++i) {
            int e = base + i * 256;
            if (e < N_EDGES) epos[e] = atomicAdd(&deg[ei[N_EDGES + e]], 1);
        }
        return;
    }
    int wid = blockIdx.x * 4 + (threadIdx.x >> 6);
    int tile = wid >> 1;
    if (tile >= GEMM_WAVES) return;
    int colbase = (wid & 1) * 128;
    int lane = threadIdx.x & 63;
    int n0 = tile * 16;
    int col = lane & 15, quad = lane >> 4;

    f32x4 acc[8];
#pragma unroll
    for (int i = 0; i < 8; ++i) acc[i] = (f32x4){0.f, 0.f, 0.f, 0.f};

    const float* xr = x + (size_t)(n0 + col) * 128 + quad * 8;
    const ushort_t* wbase = wgbT + (size_t)(colbase + col) * 128 + quad * 8;
#pragma unroll
    for (int kk = 0; kk < 4; ++kk) {
        float4 xa = *(const float4*)(xr + kk * 32);
        float4 xb = *(const float4*)(xr + kk * 32 + 4);
        short8 af;   // B-operand: B[k][node]
        af[0] = (short)f2bf(xa.x); af[1] = (short)f2bf(xa.y);
        af[2] = (short)f2bf(xa.z); af[3] = (short)f2bf(xa.w);
        af[4] = (short)f2bf(xb.x); af[5] = (short)f2bf(xb.y);
        af[6] = (short)f2bf(xb.z); af[7] = (short)f2bf(xb.w);
#pragma unroll
        for (int nt = 0; nt < 8; ++nt) {
            short8 wf = *(const short8*)(wbase + nt * 16 * 128 + kk * 32); // A[ch][k]
            acc[nt] = __builtin_amdgcn_mfma_f32_16x16x32_bf16(wf, af, acc[nt], 0, 0, 0);
        }
    }

    // ---- hb store: lane owns node n0+col; regs hold ch = colbase+nt*16+quad*4+r ----
    int node = n0 + col;
    ushort_t* hrow = hb + (size_t)node * 256 + colbase + quad * 4;
#pragma unroll
    for (int nt = 0; nt < 8; ++nt) {
        uint2 o;
        o.x = (uint_t)f2bf(acc[nt][0]) | ((uint_t)f2bf(acc[nt][1]) << 16);
        o.y = (uint_t)f2bf(acc[nt][2]) | ((uint_t)f2bf(acc[nt][3]) << 16);
        *(uint2*)(hrow + nt * 16) = o;
    }

    // ---- a_s/a_d (node-major): 4 local heads; lane-local dot, reduce over quads ----
#pragma unroll
    for (int hl = 0; hl < 4; ++hl) {
        int hg = (colbase >> 5) + hl;
        float4 s0 = *(const float4*)(att_s + colbase + hl * 32 + quad * 4);
        float4 s1 = *(const float4*)(att_s + colbase + hl * 32 + 16 + quad * 4);
        float4 d0 = *(const float4*)(att_d + colbase + hl * 32 + quad * 4);
        float4 d1 = *(const float4*)(att_d + colbase + hl * 32 + 16 + quad * 4);
        f32x4 e = acc[2 * hl], f = acc[2 * hl + 1];
        float ps = e[0]*s0.x + e[1]*s0.y + e[2]*s0.z + e[3]*s0.w
                 + f[0]*s1.x + f[1]*s1.y + f[2]*s1.z + f[3]*s1.w;
        float pd = e[0]*d0.x + e[1]*d0.y + e[2]*d0.z + e[3]*d0.w
                 + f[0]*d1.x + f[1]*d1.y + f[2]*d1.z + f[3]*d1.w;
        ps += __shfl_xor(ps, 16, 64); ps += __shfl_xor(ps, 32, 64);
        pd += __shfl_xor(pd, 16, 64); pd += __shfl_xor(pd, 32, 64);
        if (quad == 0) {
            a_s[(size_t)node * 8 + hg] = ps;
            a_d[(size_t)node * 8 + hg] = pd;
        }
    }
}

__global__ __launch_bounds__(256) void k_scan1(const int* __restrict__ deg,
                                               int* __restrict__ row,
                                               int* __restrict__ bsum) {
    __shared__ int s[256];
    int t = threadIdx.x;
    int i = blockIdx.x * 256 + t;
    int v = (i < N_NODES) ? deg[i] : 0;
    s[t] = v;
    __syncthreads();
    for (int off = 1; off < 256; off <<= 1) {
        int u = (t >= off) ? s[t - off] : 0;
        __syncthreads();
        s[t] += u;
        __syncthreads();
    }
    if (i < N_NODES) row[i] = s[t] - v;       // exclusive, block-local
    if (t == 255) bsum[blockIdx.x] = s[255];
}

__global__ __launch_bounds__(256) void k_scan2(int* __restrict__ bsum,
                                               const int* __restrict__ batch,
                                               int* __restrict__ gs) {
    __shared__ int s[256];
    int t = threadIdx.x;
    int v = (t < SCAN_BLOCKS) ? bsum[t] : 0;
    s[t] = v;
    __syncthreads();
    for (int off = 1; off < 256; off <<= 1) {
        int u = (t >= off) ? s[t - off] : 0;
        __syncthreads();
        s[t] += u;
        __syncthreads();
    }
    if (t < SCAN_BLOCKS) bsum[t] = s[t] - v;  // exclusive
    if (t <= NG) {
        int lo = 0, hi = N_NODES;
        while (lo < hi) {
            int mid = (lo + hi) >> 1;
            if (batch[mid] < t) lo = mid + 1; else hi = mid;
        }
        gs[t] = lo;
    }
}

// scatter: pure permutation write, zero atomics. row is block-local; add bsum inline
__global__ __launch_bounds__(256, 8) void k_scatter(const int* __restrict__ ei,
                                                    const int* __restrict__ row,
                                                    const int* __restrict__ bsum,
                                                    const int* __restrict__ epos,
                                                    int* __restrict__ csr) {
    int e = blockIdx.x * 256 + threadIdx.x;
    if (e >= N_EDGES) return;
    int d = ei[N_EDGES + e];
    csr[row[d] + bsum[d >> 8] + epos[e]] = ei[e];
}

// ---------- fused GAT: single-pass softmax+gather, TWO edges per wave-pass ----------
// R2 structure (best known: ~69us). 32 lanes x 16B (uint4 = 8 channels) cover one
// 512B hb row; the two half-waves process even/odd CSR slots concurrently.
// R3 proved the ~70us plateau is a latency x miss-queue bound on LLC-line gathers,
// NOT issue-bound -> this round adds __launch_bounds__(256,8) to raise occupancy
// (was 65% at 32 VGPR) and deepen memory-level parallelism.
__global__ __launch_bounds__(256, 8) void k_gat(const int* __restrict__ row,
                                                const int* __restrict__ bsum,
                                                const int* __restrict__ csr,
                                                const float* __restrict__ a_s,
                                                const float* __restrict__ a_d,
                                                const ushort_t* __restrict__ hb,
                                                const float* __restrict__ bg,
                                                ushort_t* __restrict__ outb) {
    int g = threadIdx.x >> 6;
    int lane = threadIdx.x & 63;
    int n = blockIdx.x * 4 + g;            // N_NODES % 4 == 0
    int r0 = row[n] + bsum[n >> 8];
    int r1 = (n + 1 < N_NODES) ? row[n + 1] + bsum[(n + 1) >> 8] : N_EDGES;
    int deg = r1 - r0;

    int c    = lane & 31;                  // channel group: channels c*8 .. c*8+7
    int half = lane >> 5;                  // which edge-parity this lane serves
    int hd   = c >> 2;                     // head = (c*8)/32
    float ad2 = a_d[n * 8 + hd];
    const char* as_hd = (const char*)(a_s + hd);        // +src*32B
    const char* hlane = (const char*)hb + c * 16;       // +src*512B
    const int* cp = csr + r0;

    float acc[8];
    float psum;
    {   // implicit self loop, counted once (half 0 carries it)
        float vs = *(const float*)(as_hd + ((size_t)n << 5)) + ad2;
        vs = vs > 0.f ? vs : 0.2f * vs;
        float evs = __expf(vs);
        float w = (half == 0) ? evs : 0.f;
        uint4 su = *(const uint4*)(hlane + ((size_t)n << 9));
        acc[0] = w * bf_lo(su.x); acc[1] = w * bf_hi(su.x);
        acc[2] = w * bf_lo(su.y); acc[3] = w * bf_hi(su.y);
        acc[4] = w * bf_lo(su.z); acc[5] = w * bf_hi(su.z);
        acc[6] = w * bf_lo(su.w); acc[7] = w * bf_hi(su.w);
        psum = w;
    }

    int j = half;
    for (; j + 6 < deg; j += 8) {          // 4 edges per half per batch
        int   sx[4];
        float av[4];
        uint4 uu[4];
#pragma unroll
        for (int i = 0; i < 4; ++i) sx[i] = cp[j + 2 * i];
#pragma unroll
        for (int i = 0; i < 4; ++i) av[i] = *(const float*)(as_hd + ((size_t)sx[i] << 5));
#pragma unroll
        for (int i = 0; i < 4; ++i) uu[i] = *(const uint4*)(hlane + ((size_t)sx[i] << 9));
#pragma unroll
        for (int i = 0; i < 4; ++i) {
            float v = av[i] + ad2;
            v = v > 0.f ? v : 0.2f * v;
            float ev = __expf(v);
            psum += ev;
            acc[0] = fmaf(ev, bf_lo(uu[i].x), acc[0]);
            acc[1] = fmaf(ev, bf_hi(uu[i].x), acc[1]);
            acc[2] = fmaf(ev, bf_lo(uu[i].y), acc[2]);
            acc[3] = fmaf(ev, bf_hi(uu[i].y), acc[3]);
            acc[4] = fmaf(ev, bf_lo(uu[i].z), acc[4]);
            acc[5] = fmaf(ev, bf_hi(uu[i].z), acc[5]);
            acc[6] = fmaf(ev, bf_lo(uu[i].w), acc[6]);
            acc[7] = fmaf(ev, bf_hi(uu[i].w), acc[7]);
        }
    }
    for (; j < deg; j += 2) {
        int sj = cp[j];
        float v = *(const float*)(as_hd + ((size_t)sj << 5)) + ad2;
        v = v > 0.f ? v : 0.2f * v;
        float ev = __expf(v);
        psum += ev;
        uint4 u = *(const uint4*)(hlane + ((size_t)sj << 9));
        acc[0] = fmaf(ev, bf_lo(u.x), acc[0]);
        acc[1] = fmaf(ev, bf_hi(u.x), acc[1]);
        acc[2] = fmaf(ev, bf_lo(u.y), acc[2]);
        acc[3] = fmaf(ev, bf_hi(u.y), acc[3]);
        acc[4] = fmaf(ev, bf_lo(u.z), acc[4]);
        acc[5] = fmaf(ev, bf_hi(u.z), acc[5]);
        acc[6] = fmaf(ev, bf_lo(u.w), acc[6]);
        acc[7] = fmaf(ev, bf_hi(u.w), acc[7]);
    }

    // merge the two edge-parities (per node, not per edge)
    psum += __shfl_xor(psum, 32, 64);
#pragma unroll
    for (int k = 0; k < 8; ++k) acc[k] += __shfl_xor(acc[k], 32, 64);

    float inv = 1.0f / psum;
    float4 b0 = *(const float4*)(bg + c * 8);
    float4 b1 = *(const float4*)(bg + c * 8 + 4);
    float o0 = fmaxf(fmaf(acc[0], inv, b0.x), 0.f);
    float o1 = fmaxf(fmaf(acc[1], inv, b0.y), 0.f);
    float o2 = fmaxf(fmaf(acc[2], inv, b0.z), 0.f);
    float o3 = fmaxf(fmaf(acc[3], inv, b0.w), 0.f);
    float o4 = fmaxf(fmaf(acc[4], inv, b1.x), 0.f);
    float o5 = fmaxf(fmaf(acc[5], inv, b1.y), 0.f);
    float o6 = fmaxf(fmaf(acc[6], inv, b1.z), 0.f);
    float o7 = fmaxf(fmaf(acc[7], inv, b1.w), 0.f);
    uint4 o;
    o.x = (uint_t)f2bf(o0) | ((uint_t)f2bf(o1) << 16);
    o.y = (uint_t)f2bf(o2) | ((uint_t)f2bf(o3) << 16);
    o.z = (uint_t)f2bf(o4) | ((uint_t)f2bf(o5) << 16);
    o.w = (uint_t)f2bf(o6) | ((uint_t)f2bf(o7) << 16);
    if (half == 0)
        *(uint4*)((char*)outb + ((size_t)n << 9) + c * 16) = o;
}

// ---------- MFMA projection: y = out_bf @ W1  (50000x256x32), bf16 output ----------
__global__ __launch_bounds__(256) void k_gemm_y(const ushort_t* __restrict__ outb,
                                                const ushort_t* __restrict__ w1bT,
                                                ushort_t* __restrict__ yb) {
    int wave = blockIdx.x * 4 + (threadIdx.x >> 6);
    if (wave >= GEMM_WAVES) return;
    int lane = threadIdx.x & 63;
    int n0 = wave * 16;
    int col = lane & 15, quad = lane >> 4;

    f32x4 acc0 = (f32x4){0.f, 0.f, 0.f, 0.f};
    f32x4 acc1 = (f32x4){0.f, 0.f, 0.f, 0.f};
    const ushort_t* ar = outb + (size_t)(n0 + col) * 256 + quad * 8;
    const ushort_t* b0 = w1bT + col * 256 + quad * 8;
    const ushort_t* b1 = w1bT + (16 + col) * 256 + quad * 8;
#pragma unroll
    for (int kk = 0; kk < 8; ++kk) {
        short8 af  = *(const short8*)(ar + kk * 32);
        short8 bf0 = *(const short8*)(b0 + kk * 32);
        short8 bf1 = *(const short8*)(b1 + kk * 32);
        acc0 = __builtin_amdgcn_mfma_f32_16x16x32_bf16(af, bf0, acc0, 0, 0, 0);
        acc1 = __builtin_amdgcn_mfma_f32_16x16x32_bf16(af, bf1, acc1, 0, 0, 0);
    }
    ushort_t* yr = yb + (size_t)(n0 + quad * 4) * 32 + col;
#pragma unroll
    for (int r = 0; r < 4; ++r) {
        yr[r * 32]      = f2bf(acc0[r]);
        yr[r * 32 + 16] = f2bf(acc1[r]);
    }
}

// ---------- GIN on bf16 y (64 B rows, L2-resident) + MLP layer 2 ----------
__global__ __launch_bounds__(256) void k_gin_mlp(const int* __restrict__ row,
                                                 const int* __restrict__ bsum,
                                                 const int* __restrict__ csr,
                                                 const ushort_t* __restrict__ yb,
                                                 const float* __restrict__ b1,
                                                 const float* __restrict__ W2,
                                                 const float* __restrict__ b2,
                                                 float* __restrict__ z) {
    __shared__ float s_z[4][32];
    int g = threadIdx.x >> 6;
    int lane = threadIdx.x & 63;
    int n = blockIdx.x * 4 + g;
    int col = lane & 31, half = lane >> 5;
    int r0 = row[n] + bsum[n >> 8];
    int r1 = (n + 1 < N_NODES) ? row[n + 1] + bsum[(n + 1) >> 8] : N_EDGES;
    const char* ycol = (const char*)(yb + col);     // +sj*64B
    float acc = (half == 0) ? (bf2f(yb[(size_t)n * 32 + col]) + b1[col]) : 0.f;
    int j = r0 + half;                              // this half-wave's edges: stride 2
    for (; j + 6 < r1; j += 8) {
        int s0 = csr[j], s1 = csr[j + 2], s2 = csr[j + 4], s3 = csr[j + 6];
        float v0 = bf2f(*(const ushort_t*)(ycol + ((size_t)s0 << 6)));
        float v1 = bf2f(*(const ushort_t*)(ycol + ((size_t)s1 << 6)));
        float v2 = bf2f(*(const ushort_t*)(ycol + ((size_t)s2 << 6)));
        float v3 = bf2f(*(const ushort_t*)(ycol + ((size_t)s3 << 6)));
        acc += (v0 + v1) + (v2 + v3);
    }
    for (; j < r1; j += 2)
        acc += bf2f(*(const ushort_t*)(ycol + ((size_t)csr[j] << 6)));
    acc += __shfl_xor(acc, 32, 64);
    float z1 = fmaxf(acc, 0.f);
    if (lane < 32) s_z[g][col] = z1;               // wave-private; no barrier
    const float* zr = &s_z[g][0];
    int k0 = half * 16;
    float p = 0.f;
#pragma unroll
    for (int k = 0; k < 16; k += 4) {
        float4 zv = *(const float4*)(zr + k0 + k);
        p = fmaf(zv.x, W2[(k0 + k + 0) * 32 + col], p);
        p = fmaf(zv.y, W2[(k0 + k + 1) * 32 + col], p);
        p = fmaf(zv.z, W2[(k0 + k + 2) * 32 + col], p);
        p = fmaf(zv.w, W2[(k0 + k + 3) * 32 + col], p);
    }
    p += __shfl_xor(p, 32, 64);
    if (lane < 32) z[n * 32 + col] = fmaxf(p + b2[col], 0.f);
}

// one block per graph: mean-pool its contiguous z rows, then @Wf + bf
__global__ __launch_bounds__(128) void k_pool_final(const float* __restrict__ z,
                                                    const int* __restrict__ gs,
                                                    const float* __restrict__ Wf,
                                                    const float* __restrict__ bf,
                                                    float* __restrict__ outp) {
    __shared__ float part[4][32];
    __shared__ float sums[32];
    int g = blockIdx.x;
    int t = threadIdx.x;
    int col = t & 31, q = t >> 5;
    int r0 = gs[g], r1 = gs[g + 1];
    float s = 0.f;
    for (int r = r0 + q; r < r1; r += 4) s += z[r * 32 + col];
    part[q][col] = s;
    __syncthreads();
    if (t < 32) sums[t] = part[0][t] + part[1][t] + part[2][t] + part[3][t];
    __syncthreads();
    float inv = 1.0f / fmaxf((float)(r1 - r0), 1.0f);
    float acc = 0.f;
#pragma unroll
    for (int k = 0; k < 32; ++k)
        acc = fmaf(sums[k], Wf[k * 128 + t], acc);
    outp[g * 128 + t] = acc * inv + bf[t];
}

extern "C" void kernel_launch(void* const* d_in, const int* in_sizes, int n_in,
                              void* d_out, int out_size, void* d_ws, size_t ws_size,
                              hipStream_t stream) {
    const float* x     = (const float*)d_in[0];
    const int*   ei    = (const int*)d_in[1];
    const int*   batch = (const int*)d_in[2];
    const float* Wg    = (const float*)d_in[3];
    const float* att_s = (const float*)d_in[4];
    const float* att_d = (const float*)d_in[5];
    const float* bg    = (const float*)d_in[6];
    const float* W1    = (const float*)d_in[7];
    const float* b1    = (const float*)d_in[8];
    const float* W2    = (const float*)d_in[9];
    const float* b2    = (const float*)d_in[10];
    const float* Wf    = (const float*)d_in[11];
    const float* bf    = (const float*)d_in[12];
    float* ws = (float*)d_ws;

    ushort_t* hb   = (ushort_t*)(ws + HB_OFF);
    ushort_t* yb   = (ushort_t*)(ws + Y_OFF);
    float* z       = ws + Z_OFF;
    float* a_s     = ws + AS_OFF;
    float* a_d     = ws + AD_OFF;
    int*   row     = (int*)(ws + ROW_OFF);
    int*   deg     = (int*)(ws + DEG_OFF);
    int*   csr     = (int*)(ws + CSR_OFF);
    int*   gs      = (int*)(ws + GS_OFF);
    int*   bsum    = (int*)(ws + BSUM_OFF);
    ushort_t* wgbT = (ushort_t*)(ws + WGBT_OFF);
    ushort_t* w1bT = (ushort_t*)(ws + W1BT_OFF);
    int*   epos    = (int*)(ws + EPOS_OFF);
    ushort_t* outb = (ushort_t*)(ws + OUTB_OFF);

    // init: wgbT + zero deg + w1bT (one launch)
    k_init<<<(32768 + 12500 + 8192 + 255) / 256, 256, 0, stream>>>(Wg, W1, wgbT, w1bT, (float*)deg);

    // fused: MFMA projection (hb, a_s, a_d) || batched edge histogram
    k_gemm_hist<<<GEMM_BLOCKS2 + HIST_BLOCKS2, 256, 0, stream>>>(
        x, wgbT, att_s, att_d, hb, a_s, a_d, ei, deg, epos);

    // CSR: scans + atomic-free scatter
    k_scan1<<<SCAN_BLOCKS, 256, 0, stream>>>(deg, row, bsum);
    k_scan2<<<1, 256, 0, stream>>>(bsum, batch, gs);
    k_scatter<<<(N_EDGES + 255) / 256, 256, 0, stream>>>(ei, row, bsum, epos, csr);

    // fused GAT: single-pass softmax+gather (R2 structure + occupancy bound)
    k_gat<<<N_NODES / 4, 256, 0, stream>>>(row, bsum, csr, a_s, a_d, hb, bg, outb);
    // MFMA projection y = out_bf @ W1 (bf16 out, L2-resident for GIN)
    k_gemm_y<<<(GEMM_WAVES + 3) / 4, 256, 0, stream>>>(outb, w1bT, yb);

    // GIN on bf16 y + MLP layer 2 -> z (one wave per node, no barriers)
    k_gin_mlp<<<N_NODES / 4, 256, 0, stream>>>(row, bsum, csr, yb, b1, W2, b2, z);

    // per-graph mean pool + final linear
    k_pool_final<<<NG, 128, 0, stream>>>(z, gs, Wf, bf, (float*)d_out);
}